// Round 5
// baseline (423.064 us; speedup 1.0000x reference)
//
#include <hip/hip_runtime.h>
#include <hip/hip_cooperative_groups.h>
#include <stdint.h>

namespace cg = cooperative_groups;

#define M_ROWS 4096   // BATCH*SEQ
#define N_OUT  4096   // OUT_FEATURES
#define K_IN   4096   // IN_FEATURES
#define NNZ_N  1677722
#define NBLK   256    // prep blocks (1 per CU, co-resident)
#define CHUNK  6560   // ceil(NNZ/NBLK) rounded; 256*6560 = 1679360 >= NNZ
#define NBINS  512    // row bins of 8 rows each

typedef __attribute__((ext_vector_type(8))) short  bf16x8_t;  // 8 bf16 in 4 VGPRs
typedef __attribute__((ext_vector_type(4))) float  f32x4_t;

// ---------- fp32 -> bf16 (RNE) ----------
__device__ __forceinline__ unsigned short f2bf(float f) {
    union { float f; uint32_t u; } v; v.f = f;
    uint32_t u = v.u;
    u += 0x7FFFu + ((u >> 16) & 1u);   // round-to-nearest-even
    return (unsigned short)(u >> 16);
}

// ================= fused prep: convert x + sort COO + accumulate W =================
// mask bit0 = phase A (convert + local sort), bit1 = phase B (accumulate+write W).
// mask==3 requires cooperative launch (grid.sync between phases).
// LDS: pool 128 KiB (sort ebuf / accum rows, aliased) + hist/basev/curv 6 KiB.
__global__ __launch_bounds__(1024, 1) void prep_fused(
        const float4* __restrict__ x, const float* __restrict__ data,
        const int* __restrict__ rows, const int* __restrict__ cols,
        uint4* __restrict__ xo, uint32_t* __restrict__ run,
        uint32_t* __restrict__ Fbase, unsigned short* __restrict__ W, int mask) {
    __shared__ __align__(16) float pool[8 * K_IN];        // 128 KiB
    __shared__ uint32_t hist[NBINS], basev[NBINS], curv[NBINS];
    const int blk = blockIdx.x, t = threadIdx.x;
    const int wave = t >> 6, lane = t & 63;

    if (mask & 1) {
        // ---- A1: convert x -> bf16, grid-stride (8 iters) ----
        const int gsz = NBLK * 1024;                       // 262144
        for (int i = blk * 1024 + t; i < M_ROWS * K_IN / 8; i += gsz) {
            float4 a = x[2 * i], b = x[2 * i + 1];
            uint4 o;
            o.x = (uint32_t)f2bf(a.x) | ((uint32_t)f2bf(a.y) << 16);
            o.y = (uint32_t)f2bf(a.z) | ((uint32_t)f2bf(a.w) << 16);
            o.z = (uint32_t)f2bf(b.x) | ((uint32_t)f2bf(b.y) << 16);
            o.w = (uint32_t)f2bf(b.z) | ((uint32_t)f2bf(b.w) << 16);
            xo[i] = o;
        }
        // ---- A2: block-local counting sort of chunk (LDS-only scatter) ----
        uint32_t* ebuf = (uint32_t*)pool;                  // <= 6560 entries
        const int start = blk * CHUNK;
        const int end   = (start + CHUNK < NNZ_N) ? start + CHUNK : NNZ_N;
        const int nloc  = end - start;
        for (int j = t; j < NBINS; j += 1024) hist[j] = 0;
        __syncthreads();
        for (int i = start + t; i < end; i += 1024)
            atomicAdd(&hist[rows[i] >> 3], 1u);            // native ds_add u32
        __syncthreads();
        if (t < 64) {   // wave 0: 512-bin exclusive scan
            uint32_t pre[8], loc = 0;
#pragma unroll
            for (int q = 0; q < 8; ++q) { pre[q] = loc; loc += hist[t * 8 + q]; }
            uint32_t xv = loc;
#pragma unroll
            for (int off = 1; off < 64; off <<= 1) {
                uint32_t y = __shfl_up(xv, off);
                if (t >= off) xv += y;
            }
            uint32_t excl = xv - loc;
#pragma unroll
            for (int q = 0; q < 8; ++q) {
                basev[t * 8 + q] = excl + pre[q];
                curv[t * 8 + q]  = excl + pre[q];
            }
        }
        __syncthreads();
        for (int i = start + t; i < end; i += 1024) {
            int r = rows[i];
            uint32_t slot = atomicAdd(&curv[r >> 3], 1u);
            ebuf[slot] = ((uint32_t)(r & 7) << 28) |
                         ((uint32_t)cols[i] << 16) | (uint32_t)f2bf(data[i]);
        }
        __syncthreads();
        for (int j = t; j < nloc; j += 1024) run[start + j] = ebuf[j];
        if (t < NBINS) Fbase[(size_t)t * NBLK + blk] = basev[t];
        if (t == 0)    Fbase[(size_t)NBINS * NBLK + blk] = (uint32_t)nloc;
    }

    if (mask == 3) {
        __threadfence();                 // run/Fbase visible device-wide
        cg::this_grid().sync();
    }

    if (mask & 2) {
        // ---- B: each block accumulates 2 bins (8 rows each) and writes W ----
        uint32_t* segS = hist;           // reuse LDS
        uint32_t* segE = basev;
        float4*   av   = (float4*)pool;
#pragma unroll 1
        for (int rep = 0; rep < 2; ++rep) {
            const int f = blk * 2 + rep;
            for (int j = t; j < 8 * K_IN / 4; j += 1024)
                av[j] = (float4){0.f, 0.f, 0.f, 0.f};
            if (t < NBLK)           segS[t] = Fbase[(size_t)f * NBLK + t];
            else if (t < 2 * NBLK)  segE[t - NBLK] = Fbase[(size_t)(f + 1) * NBLK + (t - NBLK)];
            __syncthreads();
            for (int b2 = wave; b2 < NBLK; b2 += 16) {     // 16 waves split 256 segments
                uint32_t s = segS[b2], e = segE[b2];
                const uint32_t* rp = run + (size_t)b2 * CHUNK;
                for (uint32_t j = s + lane; j < e; j += 64) {
                    uint32_t en = rp[j];
                    union { uint32_t u; float fv; } v; v.u = (en & 0xFFFFu) << 16;
                    __hip_atomic_fetch_add(                 // native ds_add_f32
                        &pool[((en >> 28) & 7u) * K_IN + ((en >> 16) & 0xFFFu)],
                        v.fv, __ATOMIC_RELAXED, __HIP_MEMORY_SCOPE_WORKGROUP);
                }
            }
            __syncthreads();
            uint4* wv = (uint4*)(W + (size_t)f * 8 * K_IN); // 64 KiB coalesced
            for (int j = t; j < 8 * K_IN / 8; j += 1024) {
                float4 a = av[2 * j], c = av[2 * j + 1];
                uint4 o;
                o.x = (uint32_t)f2bf(a.x) | ((uint32_t)f2bf(a.y) << 16);
                o.y = (uint32_t)f2bf(a.z) | ((uint32_t)f2bf(a.w) << 16);
                o.z = (uint32_t)f2bf(c.x) | ((uint32_t)f2bf(c.y) << 16);
                o.w = (uint32_t)f2bf(c.z) | ((uint32_t)f2bf(c.w) << 16);
                wv[j] = o;
            }
            __syncthreads();
        }
    }
}

// ---------- async global->LDS helper (width 16B) ----------
__device__ __forceinline__ void async_ld16(const void* g, void* lds_wave_base) {
    __builtin_amdgcn_global_load_lds(
        (const __attribute__((address_space(1))) uint32_t*)g,
        (__attribute__((address_space(3))) uint32_t*)lds_wave_base,
        16, 0, 0);
}

// stage one 256x64 bf16 tile half (A or B) for K-tile kt into LDS slot:
// 4 x global_load_lds_dwordx4 per thread (512 thr x 16B x 4 = 32 KiB).
#define STAGE_M(gbase, lbase, kt, slot) do {                                   \
    const unsigned short* g_ = (gbase) + (kt) * 64;                            \
    unsigned short*       l_ = (lbase) + (slot) * 32768;                       \
    async_ld16(g_,                  l_);                                       \
    async_ld16(g_ + 1 * 64 * K_IN,  l_ + 4096);                                \
    async_ld16(g_ + 2 * 64 * K_IN,  l_ + 8192);                                \
    async_ld16(g_ + 3 * 64 * K_IN,  l_ + 12288);                               \
} while (0)

// ---------- C[M][N] = A[M][K] * B[N][K]^T, bf16 in, fp32 out ----------
// (frozen since R1: ~127 us, MfmaUtil 45%, bank conflicts 0)
__global__ __launch_bounds__(512, 2) void gemm_bt(const unsigned short* __restrict__ A,
                                                  const unsigned short* __restrict__ B,
                                                  float* __restrict__ C) {
    __shared__ __align__(16) unsigned short lds_[65536];  // 128 KiB: [A0|B0|A1|B1]

    const int t    = threadIdx.x;
    const int wave = t >> 6;
    const int lane = t & 63;
    const int wr   = wave >> 2;        // 0..1
    const int wc   = wave & 3;         // 0..3
    const int m0   = blockIdx.y * 256;
    const int n0   = blockIdx.x * 256;

    const int srow = t >> 3;
    const int sch  = ((t & 7) ^ (srow & 7)) * 8;
    const unsigned short* gA = A + (size_t)(m0 + srow) * K_IN + sch;
    const unsigned short* gB = B + (size_t)(n0 + srow) * K_IN + sch;
    unsigned short* lA = lds_ + wave * 512;
    unsigned short* lB = lds_ + 16384 + wave * 512;

    const int l15  = lane & 15;
    const int aoff = (wr * 128 + l15) * 64;
    const int boff = (wc * 64  + l15) * 64;
    const int ck0  = (((lane >> 4)    ) ^ (lane & 7)) * 8;
    const int ck1  = (((lane >> 4) | 4) ^ (lane & 7)) * 8;

    f32x4_t acc[8][4];
#pragma unroll
    for (int i = 0; i < 8; ++i)
#pragma unroll
        for (int j = 0; j < 4; ++j) acc[i][j] = (f32x4_t){0.f, 0.f, 0.f, 0.f};

    bf16x8_t af[4][2], bf0[2][2], bf1[2][2];

    STAGE_M(gA, lA, 0, 0); STAGE_M(gB, lB, 0, 0);
    STAGE_M(gA, lA, 1, 1); STAGE_M(gB, lB, 1, 1);
    asm volatile("s_waitcnt vmcnt(8)" ::: "memory");
    __builtin_amdgcn_s_barrier();

    for (int kt = 0; kt < 64; ++kt) {
        const unsigned short* pA = lds_ + (kt & 1) * 32768;
        const unsigned short* pB = pA + 16384;

        // ---------------- P1 ----------------
#pragma unroll
        for (int im = 0; im < 4; ++im) {
            af[im][0] = *(const bf16x8_t*)(pA + aoff + im * 1024 + ck0);
            af[im][1] = *(const bf16x8_t*)(pA + aoff + im * 1024 + ck1);
        }
#pragma unroll
        for (int jn = 0; jn < 2; ++jn) {
            bf0[jn][0] = *(const bf16x8_t*)(pB + boff + jn * 1024 + ck0);
            bf0[jn][1] = *(const bf16x8_t*)(pB + boff + jn * 1024 + ck1);
        }
        __builtin_amdgcn_s_barrier();
        asm volatile("s_waitcnt lgkmcnt(0)" ::: "memory");
        __builtin_amdgcn_s_setprio(1);
#pragma unroll
        for (int im = 0; im < 4; ++im)
#pragma unroll
            for (int jn = 0; jn < 2; ++jn)
#pragma unroll
                for (int kk = 0; kk < 2; ++kk)
                    acc[im][jn] = __builtin_amdgcn_mfma_f32_16x16x32_bf16(
                        af[im][kk], bf0[jn][kk], acc[im][jn], 0, 0, 0);
        __builtin_amdgcn_s_setprio(0);
        __builtin_amdgcn_s_barrier();

        // ---------------- P2 ----------------
#pragma unroll
        for (int jn = 0; jn < 2; ++jn) {
            bf1[jn][0] = *(const bf16x8_t*)(pB + boff + (2 + jn) * 1024 + ck0);
            bf1[jn][1] = *(const bf16x8_t*)(pB + boff + (2 + jn) * 1024 + ck1);
        }
        __builtin_amdgcn_s_barrier();
        asm volatile("s_waitcnt lgkmcnt(0)" ::: "memory");
        __builtin_amdgcn_s_setprio(1);
#pragma unroll
        for (int im = 0; im < 4; ++im)
#pragma unroll
            for (int jn = 0; jn < 2; ++jn)
#pragma unroll
                for (int kk = 0; kk < 2; ++kk)
                    acc[im][2 + jn] = __builtin_amdgcn_mfma_f32_16x16x32_bf16(
                        af[im][kk], bf1[jn][kk], acc[im][2 + jn], 0, 0, 0);
        __builtin_amdgcn_s_setprio(0);
        __builtin_amdgcn_s_barrier();

        // ---------------- P3 ----------------
        if (kt < 62) STAGE_M(gB, lB, kt + 2, (kt & 1));
#pragma unroll
        for (int im = 0; im < 4; ++im) {
            af[im][0] = *(const bf16x8_t*)(pA + aoff + (4 + im) * 1024 + ck0);
            af[im][1] = *(const bf16x8_t*)(pA + aoff + (4 + im) * 1024 + ck1);
        }
        __builtin_amdgcn_s_barrier();
        asm volatile("s_waitcnt lgkmcnt(0)" ::: "memory");
        __builtin_amdgcn_s_setprio(1);
#pragma unroll
        for (int im = 0; im < 4; ++im)
#pragma unroll
            for (int jn = 0; jn < 2; ++jn)
#pragma unroll
                for (int kk = 0; kk < 2; ++kk)
                    acc[4 + im][jn] = __builtin_amdgcn_mfma_f32_16x16x32_bf16(
                        af[im][kk], bf0[jn][kk], acc[4 + im][jn], 0, 0, 0);
        __builtin_amdgcn_s_setprio(0);
        __builtin_amdgcn_s_barrier();

        // ---------------- P4 ----------------
        if (kt < 62) STAGE_M(gA, lA, kt + 2, (kt & 1));
        __builtin_amdgcn_s_setprio(1);
#pragma unroll
        for (int im = 0; im < 4; ++im)
#pragma unroll
            for (int jn = 0; jn < 2; ++jn)
#pragma unroll
                for (int kk = 0; kk < 2; ++kk)
                    acc[4 + im][2 + jn] = __builtin_amdgcn_mfma_f32_16x16x32_bf16(
                        af[im][kk], bf1[jn][kk], acc[4 + im][2 + jn], 0, 0, 0);
        __builtin_amdgcn_s_setprio(0);
        if (kt < 62) {
            asm volatile("s_waitcnt vmcnt(8)" ::: "memory");
        } else {
            asm volatile("s_waitcnt vmcnt(0)" ::: "memory");
        }
        __builtin_amdgcn_s_barrier();
    }

    const int crow = m0 + wr * 128 + ((lane >> 4) << 2);
    const int ccol = n0 + wc * 64 + l15;
#pragma unroll
    for (int im = 0; im < 8; ++im)
#pragma unroll
        for (int jn = 0; jn < 4; ++jn)
#pragma unroll
            for (int r = 0; r < 4; ++r)
                C[(size_t)(crow + im * 16 + r) * N_OUT + ccol + jn * 16] =
                    acc[im][jn][r];
}

extern "C" void kernel_launch(void* const* d_in, const int* in_sizes, int n_in,
                              void* d_out, int out_size, void* d_ws, size_t ws_size,
                              hipStream_t stream) {
    const float* x    = (const float*)d_in[0];   // [2,2048,4096] fp32
    const float* data = (const float*)d_in[1];   // [NNZ]
    const int*   rows = (const int*)d_in[2];
    const int*   cols = (const int*)d_in[3];
    float*       out  = (float*)d_out;           // [2,2048,4096] fp32

    // workspace: W 32 MiB | x_bf16 32 MiB | run 6.7 MiB @64M | Fbase @72M
    unsigned short* W_bf16 = (unsigned short*)d_ws;
    unsigned short* x_bf16 = (unsigned short*)((char*)d_ws + (32u << 20));
    uint32_t*       run    = (uint32_t*)((char*)d_ws + (64u << 20));
    uint32_t*       Fbase  = (uint32_t*)((char*)d_ws + (72u << 20));

    // 1. fused prep (cooperative; fallback = two phase launches)
    const float4* x4 = (const float4*)x;
    uint4*        xo = (uint4*)x_bf16;
    int mask = 3;
    void* args[] = {(void*)&x4, (void*)&data, (void*)&rows, (void*)&cols,
                    (void*)&xo, (void*)&run, (void*)&Fbase, (void*)&W_bf16,
                    (void*)&mask};
    hipError_t e = hipLaunchCooperativeKernel((const void*)prep_fused,
                                              dim3(NBLK), dim3(1024),
                                              args, 0, stream);
    if (e != hipSuccess) {
        prep_fused<<<NBLK, 1024, 0, stream>>>(x4, data, rows, cols, xo,
                                              run, Fbase, W_bf16, 1);
        prep_fused<<<NBLK, 1024, 0, stream>>>(x4, data, rows, cols, xo,
                                              run, Fbase, W_bf16, 2);
    }

    // 2. y = x * W^T via bf16 MFMA GEMM (256x256 tile, 8-wave phase-split)
    dim3 grid(N_OUT / 256, M_ROWS / 256);  // 16 x 16 = 256 blocks = 1/CU
    gemm_bt<<<grid, 512, 0, stream>>>(x_bf16, W_bf16, out);
}

// Round 6
// 295.575 us; speedup vs baseline: 1.4313x; 1.4313x over previous
//
#include <hip/hip_runtime.h>
#include <stdint.h>

#define M_ROWS 4096   // BATCH*SEQ
#define N_OUT  4096   // OUT_FEATURES
#define K_IN   4096   // IN_FEATURES
#define NNZ_N  1677722
#define NBLK   256    // COO chunk blocks
#define CHUNK  6560   // 256*6560 = 1679360 >= NNZ
#define NBINS  1024   // row bins of 4 rows each

typedef __attribute__((ext_vector_type(8))) short  bf16x8_t;  // 8 bf16 in 4 VGPRs
typedef __attribute__((ext_vector_type(4))) float  f32x4_t;

// ---------- fp32 -> bf16 (RNE) ----------
__device__ __forceinline__ unsigned short f2bf(float f) {
    union { float f; uint32_t u; } v; v.f = f;
    uint32_t u = v.u;
    u += 0x7FFFu + ((u >> 16) & 1u);   // round-to-nearest-even
    return (unsigned short)(u >> 16);
}

// ---------- K1: convert x -> bf16 (8 elems/thread) ----------
__global__ void convert_x(const float4* __restrict__ x, uint4* __restrict__ xo) {
    int i = blockIdx.x * blockDim.x + threadIdx.x;  // exact-size grid
    float4 a = x[2 * i], b = x[2 * i + 1];
    uint4 o;
    o.x = (uint32_t)f2bf(a.x) | ((uint32_t)f2bf(a.y) << 16);
    o.y = (uint32_t)f2bf(a.z) | ((uint32_t)f2bf(a.w) << 16);
    o.z = (uint32_t)f2bf(b.x) | ((uint32_t)f2bf(b.y) << 16);
    o.w = (uint32_t)f2bf(b.z) | ((uint32_t)f2bf(b.w) << 16);
    xo[i] = o;
}

// ---------- K2: per-block LDS histogram over 1024 bins (bin = row>>2) ----------
__global__ __launch_bounds__(512) void hist_coo(const int* __restrict__ rows,
                                                uint32_t* __restrict__ Hist) {
    __shared__ uint32_t h[NBINS];   // 4 KiB
    const int blk = blockIdx.x, t = threadIdx.x;
    for (int j = t; j < NBINS; j += 512) h[j] = 0;
    __syncthreads();
    const int start = blk * CHUNK;
    const int end   = (start + CHUNK < NNZ_N) ? start + CHUNK : NNZ_N;
    for (int i = start + t; i < end; i += 512)
        atomicAdd(&h[rows[i] >> 2], 1u);            // LDS atomic
    __syncthreads();
    for (int j = t; j < NBINS; j += 512)
        Hist[(size_t)blk * NBINS + j] = h[j];       // coalesced
}

// ---------- K3a: per-bin exclusive scan over the 256 blocks (one wave/bin) ----------
// In-place Hist[blk][bin] -> within-bin block base; exact per-bin totals -> cnt.
__global__ __launch_bounds__(256) void scan_blocks(uint32_t* __restrict__ Hist,
                                                   uint32_t* __restrict__ cnt) {
    const int bin  = blockIdx.x * 4 + (threadIdx.x >> 6);
    const int lane = threadIdx.x & 63;
    uint32_t v[4], pre[4];
#pragma unroll
    for (int q = 0; q < 4; ++q)
        v[q] = Hist[(size_t)(lane * 4 + q) * NBINS + bin];
    pre[0] = 0;
#pragma unroll
    for (int q = 1; q < 4; ++q) pre[q] = pre[q - 1] + v[q - 1];
    uint32_t tot = pre[3] + v[3];
    uint32_t x = tot;
#pragma unroll
    for (int off = 1; off < 64; off <<= 1) {
        uint32_t y = __shfl_up(x, off);
        if (lane >= off) x += y;
    }
    uint32_t excl = x - tot;
#pragma unroll
    for (int q = 0; q < 4; ++q)
        Hist[(size_t)(lane * 4 + q) * NBINS + bin] = excl + pre[q];
    if (lane == 63) cnt[bin] = excl + tot;
}

// ---------- K3b: exclusive scan over the 1024 bin totals (single block) ----------
__global__ __launch_bounds__(1024) void scan_tot(const uint32_t* __restrict__ cnt,
                                                 uint32_t* __restrict__ Btot) {
    __shared__ uint32_t s[NBINS];
    const int t = threadIdx.x;
    uint32_t v = cnt[t];
    s[t] = v;
    __syncthreads();
    for (int off = 1; off < NBINS; off <<= 1) {
        uint32_t a = (t >= off) ? s[t - off] : 0u;
        __syncthreads();
        s[t] += a;
        __syncthreads();
    }
    Btot[t] = s[t] - v;                  // exclusive
    if (t == NBINS - 1) Btot[NBINS] = s[t];
}

// ---------- K4: place entries at their GLOBAL sorted position ----------
// Local sort in LDS (exact), then each entry goes straight to run[global_pos].
// Reads coalesced; scattered writes are fire-and-forget (no wave stall).
__global__ __launch_bounds__(512) void place_coo(const float* __restrict__ data,
                                                 const int* __restrict__ rows,
                                                 const int* __restrict__ cols,
                                                 const uint32_t* __restrict__ Base,
                                                 const uint32_t* __restrict__ Btot,
                                                 uint32_t* __restrict__ run) {
    __shared__ uint32_t hist2[NBINS], basev[NBINS], curv[NBINS], gbase[NBINS];
    __shared__ uint32_t ebuf[CHUNK];      // 25.6 KiB packed entries
    __shared__ uint16_t binof[CHUNK];     // 12.8 KiB bin of each slot
    const int blk = blockIdx.x, t = threadIdx.x;
    const int start = blk * CHUNK;
    const int end   = (start + CHUNK < NNZ_N) ? start + CHUNK : NNZ_N;
    const int nloc  = end - start;

    for (int j = t; j < NBINS; j += 512) {
        hist2[j] = 0;
        gbase[j] = Btot[j] + Base[(size_t)blk * NBINS + j];  // coalesced
    }
    __syncthreads();
    for (int i = start + t; i < end; i += 512)
        atomicAdd(&hist2[rows[i] >> 2], 1u);
    __syncthreads();
    if (t < 64) {   // wave 0: 1024-bin exclusive scan (16/lane + wave scan)
        uint32_t pre[16], loc = 0;
#pragma unroll
        for (int q = 0; q < 16; ++q) { pre[q] = loc; loc += hist2[t * 16 + q]; }
        uint32_t xv = loc;
#pragma unroll
        for (int off = 1; off < 64; off <<= 1) {
            uint32_t y = __shfl_up(xv, off);
            if (t >= off) xv += y;
        }
        uint32_t excl = xv - loc;
#pragma unroll
        for (int q = 0; q < 16; ++q) {
            basev[t * 16 + q] = excl + pre[q];
            curv[t * 16 + q]  = excl + pre[q];
        }
    }
    __syncthreads();
    for (int i = start + t; i < end; i += 512) {
        int r = rows[i];
        uint32_t slot = atomicAdd(&curv[r >> 2], 1u);       // LDS cursor
        ebuf[slot]  = ((uint32_t)(r & 3) << 28) |
                      ((uint32_t)cols[i] << 16) | (uint32_t)f2bf(data[i]);
        binof[slot] = (uint16_t)(r >> 2);
    }
    __syncthreads();
    for (int j = t; j < nloc; j += 512) {
        uint32_t b = binof[j];
        run[gbase[b] + (j - basev[b])] = ebuf[j];           // global sorted pos
    }
}

// ---------- K5: per-bin accumulate (ONE contiguous coalesced read) + W write ----------
// Block f owns 4 W-rows; reads run[Btot[f]..Btot[f+1]) full-lane coalesced.
__global__ __launch_bounds__(512) void accum_bins(const uint32_t* __restrict__ run,
                                                  const uint32_t* __restrict__ Btot,
                                                  unsigned short* __restrict__ W) {
    __shared__ float acc[4 * K_IN];       // 64 KiB -> 2 blocks/CU
    const int f = blockIdx.x, t = threadIdx.x;
    float4* av = (float4*)acc;
    for (int j = t; j < 4 * K_IN / 4; j += 512) av[j] = (float4){0.f, 0.f, 0.f, 0.f};
    __syncthreads();
    const uint32_t s = Btot[f], e = Btot[f + 1];
    for (uint32_t j = s + t; j < e; j += 512) {
        uint32_t en = run[j];                                // coalesced stream
        union { uint32_t u; float fv; } v; v.u = (en & 0xFFFFu) << 16;
        __hip_atomic_fetch_add(                              // native ds_add_f32
            &acc[((en >> 28) & 3u) * K_IN + ((en >> 16) & 0xFFFu)],
            v.fv, __ATOMIC_RELAXED, __HIP_MEMORY_SCOPE_WORKGROUP);
    }
    __syncthreads();
    uint4* wv = (uint4*)(W + (size_t)f * 4 * K_IN);          // 32 KiB coalesced
    for (int j = t; j < 4 * K_IN / 8; j += 512) {
        float4 a = av[2 * j], c = av[2 * j + 1];
        uint4 o;
        o.x = (uint32_t)f2bf(a.x) | ((uint32_t)f2bf(a.y) << 16);
        o.y = (uint32_t)f2bf(a.z) | ((uint32_t)f2bf(a.w) << 16);
        o.z = (uint32_t)f2bf(c.x) | ((uint32_t)f2bf(c.y) << 16);
        o.w = (uint32_t)f2bf(c.z) | ((uint32_t)f2bf(c.w) << 16);
        wv[j] = o;
    }
}

// ---------- async global->LDS helper (width 16B) ----------
__device__ __forceinline__ void async_ld16(const void* g, void* lds_wave_base) {
    __builtin_amdgcn_global_load_lds(
        (const __attribute__((address_space(1))) uint32_t*)g,
        (__attribute__((address_space(3))) uint32_t*)lds_wave_base,
        16, 0, 0);
}

// stage one 256x64 bf16 tile half (A or B) for K-tile kt into LDS slot
#define STAGE_M(gbase, lbase, kt, slot) do {                                   \
    const unsigned short* g_ = (gbase) + (kt) * 64;                            \
    unsigned short*       l_ = (lbase) + (slot) * 32768;                       \
    async_ld16(g_,                  l_);                                       \
    async_ld16(g_ + 1 * 64 * K_IN,  l_ + 4096);                                \
    async_ld16(g_ + 2 * 64 * K_IN,  l_ + 8192);                                \
    async_ld16(g_ + 3 * 64 * K_IN,  l_ + 12288);                               \
} while (0)

// ---------- C[M][N] = A[M][K] * B[N][K]^T, bf16 in, fp32 out ----------
// (frozen since R1: ~127 us, MfmaUtil 45%, bank conflicts 0)
__global__ __launch_bounds__(512, 2) void gemm_bt(const unsigned short* __restrict__ A,
                                                  const unsigned short* __restrict__ B,
                                                  float* __restrict__ C) {
    __shared__ __align__(16) unsigned short lds_[65536];  // 128 KiB: [A0|B0|A1|B1]

    const int t    = threadIdx.x;
    const int wave = t >> 6;
    const int lane = t & 63;
    const int wr   = wave >> 2;        // 0..1
    const int wc   = wave & 3;         // 0..3
    const int m0   = blockIdx.y * 256;
    const int n0   = blockIdx.x * 256;

    const int srow = t >> 3;
    const int sch  = ((t & 7) ^ (srow & 7)) * 8;
    const unsigned short* gA = A + (size_t)(m0 + srow) * K_IN + sch;
    const unsigned short* gB = B + (size_t)(n0 + srow) * K_IN + sch;
    unsigned short* lA = lds_ + wave * 512;
    unsigned short* lB = lds_ + 16384 + wave * 512;

    const int l15  = lane & 15;
    const int aoff = (wr * 128 + l15) * 64;
    const int boff = (wc * 64  + l15) * 64;
    const int ck0  = (((lane >> 4)    ) ^ (lane & 7)) * 8;
    const int ck1  = (((lane >> 4) | 4) ^ (lane & 7)) * 8;

    f32x4_t acc[8][4];
#pragma unroll
    for (int i = 0; i < 8; ++i)
#pragma unroll
        for (int j = 0; j < 4; ++j) acc[i][j] = (f32x4_t){0.f, 0.f, 0.f, 0.f};

    bf16x8_t af[4][2], bf0[2][2], bf1[2][2];

    STAGE_M(gA, lA, 0, 0); STAGE_M(gB, lB, 0, 0);
    STAGE_M(gA, lA, 1, 1); STAGE_M(gB, lB, 1, 1);
    asm volatile("s_waitcnt vmcnt(8)" ::: "memory");
    __builtin_amdgcn_s_barrier();

    for (int kt = 0; kt < 64; ++kt) {
        const unsigned short* pA = lds_ + (kt & 1) * 32768;
        const unsigned short* pB = pA + 16384;

        // ---------------- P1 ----------------
#pragma unroll
        for (int im = 0; im < 4; ++im) {
            af[im][0] = *(const bf16x8_t*)(pA + aoff + im * 1024 + ck0);
            af[im][1] = *(const bf16x8_t*)(pA + aoff + im * 1024 + ck1);
        }
#pragma unroll
        for (int jn = 0; jn < 2; ++jn) {
            bf0[jn][0] = *(const bf16x8_t*)(pB + boff + jn * 1024 + ck0);
            bf0[jn][1] = *(const bf16x8_t*)(pB + boff + jn * 1024 + ck1);
        }
        __builtin_amdgcn_s_barrier();
        asm volatile("s_waitcnt lgkmcnt(0)" ::: "memory");
        __builtin_amdgcn_s_setprio(1);
#pragma unroll
        for (int im = 0; im < 4; ++im)
#pragma unroll
            for (int jn = 0; jn < 2; ++jn)
#pragma unroll
                for (int kk = 0; kk < 2; ++kk)
                    acc[im][jn] = __builtin_amdgcn_mfma_f32_16x16x32_bf16(
                        af[im][kk], bf0[jn][kk], acc[im][jn], 0, 0, 0);
        __builtin_amdgcn_s_setprio(0);
        __builtin_amdgcn_s_barrier();

        // ---------------- P2 ----------------
#pragma unroll
        for (int jn = 0; jn < 2; ++jn) {
            bf1[jn][0] = *(const bf16x8_t*)(pB + boff + (2 + jn) * 1024 + ck0);
            bf1[jn][1] = *(const bf16x8_t*)(pB + boff + (2 + jn) * 1024 + ck1);
        }
        __builtin_amdgcn_s_barrier();
        asm volatile("s_waitcnt lgkmcnt(0)" ::: "memory");
        __builtin_amdgcn_s_setprio(1);
#pragma unroll
        for (int im = 0; im < 4; ++im)
#pragma unroll
            for (int jn = 0; jn < 2; ++jn)
#pragma unroll
                for (int kk = 0; kk < 2; ++kk)
                    acc[im][2 + jn] = __builtin_amdgcn_mfma_f32_16x16x32_bf16(
                        af[im][kk], bf1[jn][kk], acc[im][2 + jn], 0, 0, 0);
        __builtin_amdgcn_s_setprio(0);
        __builtin_amdgcn_s_barrier();

        // ---------------- P3 ----------------
        if (kt < 62) STAGE_M(gB, lB, kt + 2, (kt & 1));
#pragma unroll
        for (int im = 0; im < 4; ++im) {
            af[im][0] = *(const bf16x8_t*)(pA + aoff + (4 + im) * 1024 + ck0);
            af[im][1] = *(const bf16x8_t*)(pA + aoff + (4 + im) * 1024 + ck1);
        }
        __builtin_amdgcn_s_barrier();
        asm volatile("s_waitcnt lgkmcnt(0)" ::: "memory");
        __builtin_amdgcn_s_setprio(1);
#pragma unroll
        for (int im = 0; im < 4; ++im)
#pragma unroll
            for (int jn = 0; jn < 2; ++jn)
#pragma unroll
                for (int kk = 0; kk < 2; ++kk)
                    acc[4 + im][jn] = __builtin_amdgcn_mfma_f32_16x16x32_bf16(
                        af[im][kk], bf0[jn][kk], acc[4 + im][jn], 0, 0, 0);
        __builtin_amdgcn_s_setprio(0);
        __builtin_amdgcn_s_barrier();

        // ---------------- P4 ----------------
        if (kt < 62) STAGE_M(gA, lA, kt + 2, (kt & 1));
        __builtin_amdgcn_s_setprio(1);
#pragma unroll
        for (int im = 0; im < 4; ++im)
#pragma unroll
            for (int jn = 0; jn < 2; ++jn)
#pragma unroll
                for (int kk = 0; kk < 2; ++kk)
                    acc[4 + im][2 + jn] = __builtin_amdgcn_mfma_f32_16x16x32_bf16(
                        af[im][kk], bf1[jn][kk], acc[4 + im][2 + jn], 0, 0, 0);
        __builtin_amdgcn_s_setprio(0);
        if (kt < 62) {
            asm volatile("s_waitcnt vmcnt(8)" ::: "memory");
        } else {
            asm volatile("s_waitcnt vmcnt(0)" ::: "memory");
        }
        __builtin_amdgcn_s_barrier();
    }

    const int crow = m0 + wr * 128 + ((lane >> 4) << 2);
    const int ccol = n0 + wc * 64 + l15;
#pragma unroll
    for (int im = 0; im < 8; ++im)
#pragma unroll
        for (int jn = 0; jn < 4; ++jn)
#pragma unroll
            for (int r = 0; r < 4; ++r)
                C[(size_t)(crow + im * 16 + r) * N_OUT + ccol + jn * 16] =
                    acc[im][jn][r];
}

extern "C" void kernel_launch(void* const* d_in, const int* in_sizes, int n_in,
                              void* d_out, int out_size, void* d_ws, size_t ws_size,
                              hipStream_t stream) {
    const float* x    = (const float*)d_in[0];   // [2,2048,4096] fp32
    const float* data = (const float*)d_in[1];   // [NNZ]
    const int*   rows = (const int*)d_in[2];
    const int*   cols = (const int*)d_in[3];
    float*       out  = (float*)d_out;           // [2,2048,4096] fp32

    // workspace layout:
    //   W_bf16 32 MiB @ 0 | x_bf16 32 MiB @ 32M | Hist/Base 1 MiB @ 64M
    //   cnt 4 KiB @ 66M | Btot 4+ KiB @ 66M+64K | run 6.7 MiB @ 68M
    unsigned short* W_bf16 = (unsigned short*)d_ws;
    unsigned short* x_bf16 = (unsigned short*)((char*)d_ws + (32u << 20));
    uint32_t*       Hist   = (uint32_t*)((char*)d_ws + (64u << 20));
    uint32_t*       cnt    = (uint32_t*)((char*)d_ws + (66u << 20));
    uint32_t*       Btot   = (uint32_t*)((char*)d_ws + (66u << 20) + (64u << 10));
    uint32_t*       run    = (uint32_t*)((char*)d_ws + (68u << 20));

    // 1. convert x -> bf16
    convert_x<<<(M_ROWS * K_IN) / (8 * 256), 256, 0, stream>>>(
        (const float4*)x, (uint4*)x_bf16);

    // 2. per-block 1024-bin histogram
    hist_coo<<<NBLK, 512, 0, stream>>>(rows, Hist);

    // 3a. per-bin scan over blocks; 3b. scan over bin totals
    scan_blocks<<<NBINS / 4, 256, 0, stream>>>(Hist, cnt);
    scan_tot<<<1, NBINS, 0, stream>>>(cnt, Btot);

    // 4. place entries at global sorted positions (coalesced reads, LDS sort)
    place_coo<<<NBLK, 512, 0, stream>>>(data, rows, cols, Hist, Btot, run);

    // 5. per-bin accumulate (contiguous coalesced read) -> dense bf16 W
    accum_bins<<<NBINS, 512, 0, stream>>>(run, Btot, W_bf16);

    // 6. y = x * W^T via bf16 MFMA GEMM
    dim3 grid(N_OUT / 256, M_ROWS / 256);  // 16 x 16 = 256 blocks = 1/CU
    gemm_bt<<<grid, 512, 0, stream>>>(x_bf16, W_bf16, out);
}

// Round 7
// 288.483 us; speedup vs baseline: 1.4665x; 1.0246x over previous
//
#include <hip/hip_runtime.h>
#include <stdint.h>

#define M_ROWS 4096   // BATCH*SEQ
#define N_OUT  4096   // OUT_FEATURES
#define K_IN   4096   // IN_FEATURES
#define NNZ_N  1677722
#define NBLK   256    // COO chunk blocks
#define CHUNK  6560   // 256*6560 = 1679360 >= NNZ
#define NBINS  1024   // row bins of 4 rows each

typedef __attribute__((ext_vector_type(8))) short  bf16x8_t;  // 8 bf16 in 4 VGPRs
typedef __attribute__((ext_vector_type(4))) float  f32x4_t;

// ---------- fp32 -> bf16 (RNE) ----------
__device__ __forceinline__ unsigned short f2bf(float f) {
    union { float f; uint32_t u; } v; v.f = f;
    uint32_t u = v.u;
    u += 0x7FFFu + ((u >> 16) & 1u);   // round-to-nearest-even
    return (unsigned short)(u >> 16);
}

// ---------- K1: fused convert x -> bf16 (grid-stride) + per-block row histogram ----------
__global__ __launch_bounds__(512) void conv_hist(const float4* __restrict__ x,
                                                 uint4* __restrict__ xo,
                                                 const int* __restrict__ rows,
                                                 uint32_t* __restrict__ Hist) {
    __shared__ uint32_t h[NBINS];   // 4 KiB
    const int blk = blockIdx.x, t = threadIdx.x;
    for (int j = t; j < NBINS; j += 512) h[j] = 0;
    // convert: 2,097,152 uint4 outputs / (256 blk * 512 thr) = 16 iters
    for (int i = blk * 512 + t; i < M_ROWS * K_IN / 8; i += NBLK * 512) {
        float4 a = x[2 * i], b = x[2 * i + 1];
        uint4 o;
        o.x = (uint32_t)f2bf(a.x) | ((uint32_t)f2bf(a.y) << 16);
        o.y = (uint32_t)f2bf(a.z) | ((uint32_t)f2bf(a.w) << 16);
        o.z = (uint32_t)f2bf(b.x) | ((uint32_t)f2bf(b.y) << 16);
        o.w = (uint32_t)f2bf(b.z) | ((uint32_t)f2bf(b.w) << 16);
        xo[i] = o;
    }
    __syncthreads();
    const int start = blk * CHUNK;
    const int end   = (start + CHUNK < NNZ_N) ? start + CHUNK : NNZ_N;
    for (int i = start + t; i < end; i += 512)
        atomicAdd(&h[rows[i] >> 2], 1u);            // LDS atomic
    __syncthreads();
    for (int j = t; j < NBINS; j += 512)
        Hist[(size_t)blk * NBINS + j] = h[j];       // coalesced
}

// ---------- K2: per-bin exclusive scan over the 256 blocks (one wave/bin) ----------
__global__ __launch_bounds__(256) void scan_blocks(uint32_t* __restrict__ Hist,
                                                   uint32_t* __restrict__ cnt) {
    const int bin  = blockIdx.x * 4 + (threadIdx.x >> 6);
    const int lane = threadIdx.x & 63;
    uint32_t v[4], pre[4];
#pragma unroll
    for (int q = 0; q < 4; ++q)
        v[q] = Hist[(size_t)(lane * 4 + q) * NBINS + bin];
    pre[0] = 0;
#pragma unroll
    for (int q = 1; q < 4; ++q) pre[q] = pre[q - 1] + v[q - 1];
    uint32_t tot = pre[3] + v[3];
    uint32_t x = tot;
#pragma unroll
    for (int off = 1; off < 64; off <<= 1) {
        uint32_t y = __shfl_up(x, off);
        if (lane >= off) x += y;
    }
    uint32_t excl = x - tot;
#pragma unroll
    for (int q = 0; q < 4; ++q)
        Hist[(size_t)(lane * 4 + q) * NBINS + bin] = excl + pre[q];
    if (lane == 63) cnt[bin] = excl + tot;
}

// ---------- K3: place entries at their GLOBAL sorted position ----------
// Computes its own 1024-bin exclusive scan of cnt (wave 0) -> no scan_tot kernel.
__global__ __launch_bounds__(512) void place_coo(const float* __restrict__ data,
                                                 const int* __restrict__ rows,
                                                 const int* __restrict__ cols,
                                                 const uint32_t* __restrict__ Base,
                                                 const uint32_t* __restrict__ cnt,
                                                 uint32_t* __restrict__ run) {
    __shared__ uint32_t hist2[NBINS], basev[NBINS], curv[NBINS];
    __shared__ uint32_t gb[NBINS], gbase[NBINS];
    __shared__ uint32_t ebuf[CHUNK];      // 25.6 KiB packed entries
    __shared__ uint16_t binof[CHUNK];     // 12.8 KiB bin of each slot
    const int blk = blockIdx.x, t = threadIdx.x;
    const int start = blk * CHUNK;
    const int end   = (start + CHUNK < NNZ_N) ? start + CHUNK : NNZ_N;
    const int nloc  = end - start;

    for (int j = t; j < NBINS; j += 512) hist2[j] = 0;
    if (t < 64) {   // wave 0: exclusive scan of cnt -> global bin bases
        uint32_t pre[16], loc = 0;
#pragma unroll
        for (int q = 0; q < 16; ++q) { pre[q] = loc; loc += cnt[t * 16 + q]; }
        uint32_t xv = loc;
#pragma unroll
        for (int off = 1; off < 64; off <<= 1) {
            uint32_t y = __shfl_up(xv, off);
            if (t >= off) xv += y;
        }
        uint32_t excl = xv - loc;
#pragma unroll
        for (int q = 0; q < 16; ++q) gb[t * 16 + q] = excl + pre[q];
    }
    __syncthreads();
    for (int i = start + t; i < end; i += 512)
        atomicAdd(&hist2[rows[i] >> 2], 1u);
    __syncthreads();
    if (t < 64) {   // wave 0: local 1024-bin exclusive scan
        uint32_t pre[16], loc = 0;
#pragma unroll
        for (int q = 0; q < 16; ++q) { pre[q] = loc; loc += hist2[t * 16 + q]; }
        uint32_t xv = loc;
#pragma unroll
        for (int off = 1; off < 64; off <<= 1) {
            uint32_t y = __shfl_up(xv, off);
            if (t >= off) xv += y;
        }
        uint32_t excl = xv - loc;
#pragma unroll
        for (int q = 0; q < 16; ++q) {
            basev[t * 16 + q] = excl + pre[q];
            curv[t * 16 + q]  = excl + pre[q];
        }
    }
    __syncthreads();
    for (int i = start + t; i < end; i += 512) {
        int r = rows[i];
        uint32_t slot = atomicAdd(&curv[r >> 2], 1u);       // LDS cursor
        ebuf[slot]  = ((uint32_t)(r & 3) << 28) |
                      ((uint32_t)cols[i] << 16) | (uint32_t)f2bf(data[i]);
        binof[slot] = (uint16_t)(r >> 2);
    }
    for (int j = t; j < NBINS; j += 512)
        gbase[j] = gb[j] + Base[(size_t)blk * NBINS + j];   // coalesced
    __syncthreads();
    for (int j = t; j < nloc; j += 512) {
        uint32_t b = binof[j];
        run[gbase[b] + (j - basev[b])] = ebuf[j];           // global sorted pos
    }
}

// ---------- K4: per-bin accumulate (contiguous coalesced read) + W write ----------
// Block f derives its own [s,e) from cnt by block-wide reduction (no Btot array).
__global__ __launch_bounds__(512) void accum_bins(const uint32_t* __restrict__ run,
                                                  const uint32_t* __restrict__ cnt,
                                                  unsigned short* __restrict__ W) {
    __shared__ float acc[4 * K_IN];       // 64 KiB -> 2 blocks/CU
    __shared__ uint32_t red[8], sE[2];
    const int f = blockIdx.x, t = threadIdx.x;
    const int wave = t >> 6, lane = t & 63;
    float4* av = (float4*)acc;
    for (int j = t; j < 4 * K_IN / 4; j += 512) av[j] = (float4){0.f, 0.f, 0.f, 0.f};
    // s = sum_{b<f} cnt[b]
    uint32_t part = 0;
    for (int j = t; j < f; j += 512) part += cnt[j];
#pragma unroll
    for (int off = 32; off > 0; off >>= 1) part += __shfl_down(part, off);
    if (lane == 0) red[wave] = part;
    __syncthreads();
    if (t == 0) {
        uint32_t s = 0;
#pragma unroll
        for (int w2 = 0; w2 < 8; ++w2) s += red[w2];
        sE[0] = s; sE[1] = s + cnt[f];
    }
    __syncthreads();
    const uint32_t s = sE[0], e = sE[1];
    for (uint32_t j = s + t; j < e; j += 512) {
        uint32_t en = run[j];                                // coalesced stream
        union { uint32_t u; float fv; } v; v.u = (en & 0xFFFFu) << 16;
        __hip_atomic_fetch_add(                              // native ds_add_f32
            &acc[((en >> 28) & 3u) * K_IN + ((en >> 16) & 0xFFFu)],
            v.fv, __ATOMIC_RELAXED, __HIP_MEMORY_SCOPE_WORKGROUP);
    }
    __syncthreads();
    uint4* wv = (uint4*)(W + (size_t)f * 4 * K_IN);          // 32 KiB coalesced
    for (int j = t; j < 4 * K_IN / 8; j += 512) {
        float4 a = av[2 * j], c = av[2 * j + 1];
        uint4 o;
        o.x = (uint32_t)f2bf(a.x) | ((uint32_t)f2bf(a.y) << 16);
        o.y = (uint32_t)f2bf(a.z) | ((uint32_t)f2bf(a.w) << 16);
        o.z = (uint32_t)f2bf(c.x) | ((uint32_t)f2bf(c.y) << 16);
        o.w = (uint32_t)f2bf(c.z) | ((uint32_t)f2bf(c.w) << 16);
        wv[j] = o;
    }
}

// ---------- async global->LDS helper (width 16B) ----------
__device__ __forceinline__ void async_ld16(const void* g, void* lds_wave_base) {
    __builtin_amdgcn_global_load_lds(
        (const __attribute__((address_space(1))) uint32_t*)g,
        (__attribute__((address_space(3))) uint32_t*)lds_wave_base,
        16, 0, 0);
}

// stage one 256x64 bf16 tile half (A or B) for K-tile kt into LDS slot
#define STAGE_M(gbase, lbase, kt, slot) do {                                   \
    const unsigned short* g_ = (gbase) + (kt) * 64;                            \
    unsigned short*       l_ = (lbase) + (slot) * 32768;                       \
    async_ld16(g_,                  l_);                                       \
    async_ld16(g_ + 1 * 64 * K_IN,  l_ + 4096);                                \
    async_ld16(g_ + 2 * 64 * K_IN,  l_ + 8192);                                \
    async_ld16(g_ + 3 * 64 * K_IN,  l_ + 12288);                               \
} while (0)

// ---------- C[M][N] = A[M][K] * B[N][K]^T, bf16 in, fp32 out ----------
// R7 change: ALL 24 fragment ds_reads issued at K-tile top (order af,bf0,bf1,af2)
// -> compiler emits COUNTED lgkm waits (12/8/0) instead of hard lgkmcnt(0) drains;
// barriers cut 8 -> 4 per K-tile (each remaining one is overwrite-protocol
// load-bearing: end-P2 guards B-region staging, end-P3 guards A-region,
// end-P4 vmcnt(8)+bar guards next-tile reads). Staging/vmcnt/swizzle unchanged.
__global__ __launch_bounds__(512, 2) void gemm_bt(const unsigned short* __restrict__ A,
                                                  const unsigned short* __restrict__ B,
                                                  float* __restrict__ C) {
    __shared__ __align__(16) unsigned short lds_[65536];  // 128 KiB: [A0|B0|A1|B1]

    const int t    = threadIdx.x;
    const int wave = t >> 6;
    const int lane = t & 63;
    const int wr   = wave >> 2;        // 0..1
    const int wc   = wave & 3;         // 0..3
    const int m0   = blockIdx.y * 256;
    const int n0   = blockIdx.x * 256;

    const int srow = t >> 3;
    const int sch  = ((t & 7) ^ (srow & 7)) * 8;
    const unsigned short* gA = A + (size_t)(m0 + srow) * K_IN + sch;
    const unsigned short* gB = B + (size_t)(n0 + srow) * K_IN + sch;
    unsigned short* lA = lds_ + wave * 512;
    unsigned short* lB = lds_ + 16384 + wave * 512;

    const int l15  = lane & 15;
    const int aoff = (wr * 128 + l15) * 64;
    const int boff = (wc * 64  + l15) * 64;
    const int ck0  = (((lane >> 4)    ) ^ (lane & 7)) * 8;
    const int ck1  = (((lane >> 4) | 4) ^ (lane & 7)) * 8;

    f32x4_t acc[8][4];
#pragma unroll
    for (int i = 0; i < 8; ++i)
#pragma unroll
        for (int j = 0; j < 4; ++j) acc[i][j] = (f32x4_t){0.f, 0.f, 0.f, 0.f};

    bf16x8_t af[4][2], af2[4][2], bf0[2][2], bf1[2][2];

    STAGE_M(gA, lA, 0, 0); STAGE_M(gB, lB, 0, 0);
    STAGE_M(gA, lA, 1, 1); STAGE_M(gB, lB, 1, 1);
    asm volatile("s_waitcnt vmcnt(8)" ::: "memory");  // K-tile0 landed
    __builtin_amdgcn_s_barrier();

    for (int kt = 0; kt < 64; ++kt) {
        const unsigned short* pA = lds_ + (kt & 1) * 32768;
        const unsigned short* pB = pA + 16384;

        // ---- K-tile top: issue ALL fragment reads (use-order: af,bf0 | bf1 | af2)
#pragma unroll
        for (int im = 0; im < 4; ++im) {
            af[im][0] = *(const bf16x8_t*)(pA + aoff + im * 1024 + ck0);
            af[im][1] = *(const bf16x8_t*)(pA + aoff + im * 1024 + ck1);
        }
#pragma unroll
        for (int jn = 0; jn < 2; ++jn) {
            bf0[jn][0] = *(const bf16x8_t*)(pB + boff + jn * 1024 + ck0);
            bf0[jn][1] = *(const bf16x8_t*)(pB + boff + jn * 1024 + ck1);
        }
#pragma unroll
        for (int jn = 0; jn < 2; ++jn) {
            bf1[jn][0] = *(const bf16x8_t*)(pB + boff + (2 + jn) * 1024 + ck0);
            bf1[jn][1] = *(const bf16x8_t*)(pB + boff + (2 + jn) * 1024 + ck1);
        }
#pragma unroll
        for (int im = 0; im < 4; ++im) {
            af2[im][0] = *(const bf16x8_t*)(pA + aoff + (4 + im) * 1024 + ck0);
            af2[im][1] = *(const bf16x8_t*)(pA + aoff + (4 + im) * 1024 + ck1);
        }

        // ---------------- P1: acc[0-3][0-1] ----------------
        __builtin_amdgcn_s_setprio(1);
#pragma unroll
        for (int im = 0; im < 4; ++im)
#pragma unroll
            for (int jn = 0; jn < 2; ++jn)
#pragma unroll
                for (int kk = 0; kk < 2; ++kk)
                    acc[im][jn] = __builtin_amdgcn_mfma_f32_16x16x32_bf16(
                        af[im][kk], bf0[jn][kk], acc[im][jn], 0, 0, 0);
        __builtin_amdgcn_s_setprio(0);
        __builtin_amdgcn_s_barrier();

        // ---------------- P2: acc[0-3][2-3] ----------------
        __builtin_amdgcn_s_setprio(1);
#pragma unroll
        for (int im = 0; im < 4; ++im)
#pragma unroll
            for (int jn = 0; jn < 2; ++jn)
#pragma unroll
                for (int kk = 0; kk < 2; ++kk)
                    acc[im][2 + jn] = __builtin_amdgcn_mfma_f32_16x16x32_bf16(
                        af[im][kk], bf1[jn][kk], acc[im][2 + jn], 0, 0, 0);
        __builtin_amdgcn_s_setprio(0);
        __builtin_amdgcn_s_barrier();   // all waves done reading B-region

        // ---------------- P3: stage B(kt+2); acc[4-7][0-1] ----------------
        if (kt < 62) STAGE_M(gB, lB, kt + 2, (kt & 1));
        __builtin_amdgcn_s_setprio(1);
#pragma unroll
        for (int im = 0; im < 4; ++im)
#pragma unroll
            for (int jn = 0; jn < 2; ++jn)
#pragma unroll
                for (int kk = 0; kk < 2; ++kk)
                    acc[4 + im][jn] = __builtin_amdgcn_mfma_f32_16x16x32_bf16(
                        af2[im][kk], bf0[jn][kk], acc[4 + im][jn], 0, 0, 0);
        __builtin_amdgcn_s_setprio(0);
        __builtin_amdgcn_s_barrier();   // all waves done reading A-region

        // ---------------- P4: stage A(kt+2); acc[4-7][2-3] ----------------
        if (kt < 62) STAGE_M(gA, lA, kt + 2, (kt & 1));
        __builtin_amdgcn_s_setprio(1);
#pragma unroll
        for (int im = 0; im < 4; ++im)
#pragma unroll
            for (int jn = 0; jn < 2; ++jn)
#pragma unroll
                for (int kk = 0; kk < 2; ++kk)
                    acc[4 + im][2 + jn] = __builtin_amdgcn_mfma_f32_16x16x32_bf16(
                        af2[im][kk], bf1[jn][kk], acc[4 + im][2 + jn], 0, 0, 0);
        __builtin_amdgcn_s_setprio(0);
        if (kt < 62) {
            asm volatile("s_waitcnt vmcnt(8)" ::: "memory");  // K-tile kt+1 landed
        } else {
            asm volatile("s_waitcnt vmcnt(0)" ::: "memory");  // drain tail
        }
        __builtin_amdgcn_s_barrier();
    }

    const int crow = m0 + wr * 128 + ((lane >> 4) << 2);
    const int ccol = n0 + wc * 64 + l15;
#pragma unroll
    for (int im = 0; im < 8; ++im)
#pragma unroll
        for (int jn = 0; jn < 4; ++jn)
#pragma unroll
            for (int r = 0; r < 4; ++r)
                C[(size_t)(crow + im * 16 + r) * N_OUT + ccol + jn * 16] =
                    acc[im][jn][r];
}

extern "C" void kernel_launch(void* const* d_in, const int* in_sizes, int n_in,
                              void* d_out, int out_size, void* d_ws, size_t ws_size,
                              hipStream_t stream) {
    const float* x    = (const float*)d_in[0];   // [2,2048,4096] fp32
    const float* data = (const float*)d_in[1];   // [NNZ]
    const int*   rows = (const int*)d_in[2];
    const int*   cols = (const int*)d_in[3];
    float*       out  = (float*)d_out;           // [2,2048,4096] fp32

    // workspace: W 32M | x_bf16 32M @32M | Hist 1M @64M | cnt 4K @66M | run @68M
    unsigned short* W_bf16 = (unsigned short*)d_ws;
    unsigned short* x_bf16 = (unsigned short*)((char*)d_ws + (32u << 20));
    uint32_t*       Hist   = (uint32_t*)((char*)d_ws + (64u << 20));
    uint32_t*       cnt    = (uint32_t*)((char*)d_ws + (66u << 20));
    uint32_t*       run    = (uint32_t*)((char*)d_ws + (68u << 20));

    // 1. fused convert x + per-block histogram
    conv_hist<<<NBLK, 512, 0, stream>>>((const float4*)x, (uint4*)x_bf16, rows, Hist);

    // 2. per-bin scan over blocks (Hist -> Base in place, totals -> cnt)
    scan_blocks<<<NBINS / 4, 256, 0, stream>>>(Hist, cnt);

    // 3. place at global sorted positions (own cnt-scan; no scan_tot kernel)
    place_coo<<<NBLK, 512, 0, stream>>>(data, rows, cols, Hist, cnt, run);

    // 4. per-bin accumulate (own prefix reduction) -> dense bf16 W
    accum_bins<<<NBINS, 512, 0, stream>>>(run, cnt, W_bf16);

    // 5. y = x * W^T via bf16 MFMA GEMM
    dim3 grid(N_OUT / 256, M_ROWS / 256);  // 16 x 16 = 256 blocks = 1/CU
    gemm_bt<<<grid, 512, 0, stream>>>(x_bf16, W_bf16, out);
}